// Round 3
// baseline (2667.513 us; speedup 1.0000x reference)
//
#include <hip/hip_runtime.h>
#include <math.h>

#define EPSQ 1e-5f
#define TOK 8192
#define DM 2048
#define DF 8192
#define NW (DM*DF)
#define NGU 16384   // concatenated gate+up output width

typedef float f32x4 __attribute__((ext_vector_type(4)));
typedef __bf16 bf16x8 __attribute__((ext_vector_type(8)));
typedef __bf16 bf16x4 __attribute__((ext_vector_type(4)));

// ---- fixed workspace layout (bytes) ----
#define OFF_DSUM 0ull                                // 3 doubles
#define OFF_SX   (4ull<<10)                          // 8192 f32
#define OFF_SH   (40ull<<10)                         // 8192 f32
#define OFF_XQ   (1ull<<20)                          // 32MB bf16 [8192][2048]
#define OFF_WGQ  (OFF_XQ  + (32ull<<20))             // 32MB bf16 [8192][2048]
#define OFF_WUQ  (OFF_WGQ + (32ull<<20))             // 32MB (contiguous after WGQ!)
#define OFF_WDQ  (OFF_WUQ + (32ull<<20))             // 32MB bf16 [2048][8192]
#define FIXED_END (OFF_WDQ + (32ull<<20))            // 129MB
// strip region (after FIXED_END): gu fp32 [S][16384] + hq bf16 [S][8192]

#define GLL(gp, lp) __builtin_amdgcn_global_load_lds( \
    (const __attribute__((address_space(1))) unsigned int*)(gp), \
    (__attribute__((address_space(3))) unsigned int*)(lp), 16, 0, 0)

// ---- |w| sum (for absmean scale), double-precision total ----
__global__ void k_wabs(const float* __restrict__ w, double* __restrict__ dsum, int n4) {
  const f32x4* w4 = (const f32x4*)w;
  float s = 0.f;
  for (int i = blockIdx.x * blockDim.x + threadIdx.x; i < n4; i += gridDim.x * blockDim.x) {
    f32x4 v = w4[i];
    s += fabsf(v.x) + fabsf(v.y) + fabsf(v.z) + fabsf(v.w);
  }
  __shared__ float red[256];
  red[threadIdx.x] = s; __syncthreads();
  for (int o = 128; o > 0; o >>= 1) {
    if (threadIdx.x < o) red[threadIdx.x] += red[threadIdx.x + o];
    __syncthreads();
  }
  if (threadIdx.x == 0) atomicAdd(dsum, (double)red[0]);
}

// ---- ternary-quantize weights -> bf16 {-1,0,1} ----
__global__ void k_quant_w(const float* __restrict__ w, __bf16* __restrict__ wq,
                          const double* __restrict__ dsum, int n4) {
  float scale = (float)(*dsum / (double)NW) + EPSQ;
  const f32x4* w4 = (const f32x4*)w;
  for (int i = blockIdx.x * blockDim.x + threadIdx.x; i < n4; i += gridDim.x * blockDim.x) {
    f32x4 v = w4[i];
    bf16x4 o;
#pragma unroll
    for (int c = 0; c < 4; c++) {
      float q = rintf(v[c] / scale);
      q = fminf(1.f, fmaxf(-1.f, q));
      o[c] = (__bf16)q;
    }
    *(bf16x4*)&wq[(size_t)i * 4] = o;
  }
}

// ---- per-token int8 quantize x -> bf16 integer values + scale ----
__global__ void k_quant_x(const float* __restrict__ x, __bf16* __restrict__ xq,
                          float* __restrict__ sx) {
  const int row = blockIdx.x;
  const int tid = threadIdx.x;
  const f32x4* xr = (const f32x4*)(x + (size_t)row * DM);
  f32x4 v0 = xr[tid * 2], v1 = xr[tid * 2 + 1];
  float m = 0.f;
#pragma unroll
  for (int c = 0; c < 4; c++) m = fmaxf(m, fmaxf(fabsf(v0[c]), fabsf(v1[c])));
  __shared__ float red[256];
  red[tid] = m; __syncthreads();
  for (int o = 128; o > 0; o >>= 1) {
    if (tid < o) red[tid] = fmaxf(red[tid], red[tid + o]);
    __syncthreads();
  }
  float sc = fmaxf(red[0], EPSQ) / 127.f;
  if (tid == 0) sx[row] = sc;
  bf16x8 o;
#pragma unroll
  for (int c = 0; c < 4; c++) {
    float q0 = fminf(127.f, fmaxf(-128.f, rintf(v0[c] / sc)));
    float q1 = fminf(127.f, fmaxf(-128.f, rintf(v1[c] / sc)));
    o[c] = (__bf16)q0; o[c + 4] = (__bf16)q1;
  }
  *(bf16x8*)&xq[(size_t)row * DM + tid * 8] = o;
}

// ---- fused h = sigmoid(gate)*up, row-max, int8 quantize -> bf16 ints + scale ----
// gu row layout: [0,8192) = gate, [8192,16384) = up (both already fp32-scaled)
__global__ void k_gufuse(const float* __restrict__ gu, __bf16* __restrict__ hq,
                         float* __restrict__ sh) {
  const int row = blockIdx.x;
  const int tid = threadIdx.x;
  const f32x4* g4 = (const f32x4*)(gu + (size_t)row * NGU);
  const f32x4* u4 = g4 + (DF / 4);
  float h[32];
  float m = 0.f;
#pragma unroll
  for (int j = 0; j < 8; j++) {
    f32x4 g = g4[tid * 8 + j];
    f32x4 u = u4[tid * 8 + j];
#pragma unroll
    for (int c = 0; c < 4; c++) {
      float v = u[c] / (1.f + expf(-g[c]));   // sigmoid(g)*u
      h[j * 4 + c] = v;
      m = fmaxf(m, fabsf(v));
    }
  }
  __shared__ float red[256];
  red[tid] = m; __syncthreads();
  for (int o = 128; o > 0; o >>= 1) {
    if (tid < o) red[tid] = fmaxf(red[tid], red[tid + o]);
    __syncthreads();
  }
  float sc = fmaxf(red[0], EPSQ) / 127.f;
  if (tid == 0) sh[row] = sc;
#pragma unroll
  for (int jj = 0; jj < 4; jj++) {
    bf16x8 o;
#pragma unroll
    for (int c = 0; c < 8; c++) {
      float q = fminf(127.f, fmaxf(-128.f, rintf(h[jj * 8 + c] / sc)));
      o[c] = (__bf16)q;
    }
    *(bf16x8*)&hq[(size_t)row * DF + tid * 32 + jj * 8] = o;
  }
}

// ---- MFMA GEMM, both operands K-major: C[m,n] = (sum_k A[m,k]*B[n,k]) * rowscale[m] * sw ----
// sw = swA for output cols < colsplit, swB otherwise (tiles never straddle colsplit).
__global__ __launch_bounds__(256)
void k_gemm(const __bf16* __restrict__ A, const __bf16* __restrict__ B,
            float* __restrict__ C, const float* __restrict__ rowscale,
            const double* __restrict__ dsumA, const double* __restrict__ dsumB,
            int colsplit, int N, int K) {
  __shared__ __align__(16) __bf16 sA[128 * 32];
  __shared__ __align__(16) __bf16 sB[128 * 32];

  const int tid = threadIdx.x;
  const int wv = tid >> 6;
  const int lane = tid & 63;
  const int wm = wv >> 1, wn = wv & 1;
  const int lr = lane & 15;
  const int lkb = (lane >> 4) * 8;

  const int m0 = blockIdx.y * 128;
  const int n0 = blockIdx.x * 128;

  const float sw = (n0 < colsplit)
      ? (float)(*dsumA / (double)NW) + EPSQ
      : (float)(*dsumB / (double)NW) + EPSQ;

  const int srow = tid >> 2;
  const int scol = (tid & 3) * 8;
  const int ldsw = wv * 512;  // wave-uniform LDS staging base (elements)

  f32x4 acc[4][4];
  const f32x4 z4 = {0.f, 0.f, 0.f, 0.f};
#pragma unroll
  for (int i = 0; i < 4; i++)
#pragma unroll
    for (int j = 0; j < 4; j++) acc[i][j] = z4;

  const __bf16* gA = A + (size_t)(m0 + srow) * K + scol;
  const __bf16* gB = B + (size_t)(n0 + srow) * K + scol;
  const size_t rstep = (size_t)64 * K;

  for (int k0 = 0; k0 < K; k0 += 32) {
    GLL(gA + k0, &sA[ldsw]);
    GLL(gA + k0 + rstep, &sA[2048 + ldsw]);
    GLL(gB + k0, &sB[ldsw]);
    GLL(gB + k0 + rstep, &sB[2048 + ldsw]);
    __syncthreads();

    bf16x8 af[4], bfr[4];
#pragma unroll
    for (int m = 0; m < 4; m++)
      af[m] = *(const bf16x8*)&sA[(wm * 64 + m * 16 + lr) * 32 + lkb];
#pragma unroll
    for (int n = 0; n < 4; n++)
      bfr[n] = *(const bf16x8*)&sB[(wn * 64 + n * 16 + lr) * 32 + lkb];
#pragma unroll
    for (int m = 0; m < 4; m++)
#pragma unroll
      for (int n = 0; n < 4; n++)
        acc[m][n] = __builtin_amdgcn_mfma_f32_16x16x32_bf16(af[m], bfr[n], acc[m][n], 0, 0, 0);
    __syncthreads();
  }

  // epilogue: C/D layout col = lane&15, row = (lane>>4)*4 + j
  float rs[4][4];
#pragma unroll
  for (int m = 0; m < 4; m++)
#pragma unroll
    for (int j = 0; j < 4; j++)
      rs[m][j] = rowscale[m0 + wm * 64 + m * 16 + (lane >> 4) * 4 + j] * sw;

#pragma unroll
  for (int m = 0; m < 4; m++)
#pragma unroll
    for (int n = 0; n < 4; n++)
#pragma unroll
      for (int j = 0; j < 4; j++) {
        int row = m0 + wm * 64 + m * 16 + (lane >> 4) * 4 + j;
        int col = n0 + wn * 64 + n * 16 + lr;
        C[(size_t)row * N + col] = acc[m][n][j] * rs[m][j];
      }
}

extern "C" void kernel_launch(void* const* d_in, const int* in_sizes, int n_in,
                              void* d_out, int out_size, void* d_ws, size_t ws_size,
                              hipStream_t stream) {
  const float* x  = (const float*)d_in[0];
  const float* wg = (const float*)d_in[1];
  const float* wu = (const float*)d_in[2];
  const float* wd = (const float*)d_in[3];
  float* out = (float*)d_out;
  char* ws = (char*)d_ws;

  double* dsum = (double*)(ws + OFF_DSUM);
  float* sx = (float*)(ws + OFF_SX);
  float* sh = (float*)(ws + OFF_SH);
  __bf16* xq  = (__bf16*)(ws + OFF_XQ);
  __bf16* wgq = (__bf16*)(ws + OFF_WGQ);  // wgq..wuq contiguous = [16384][2048]
  __bf16* wuq = (__bf16*)(ws + OFF_WUQ);
  __bf16* wdq = (__bf16*)(ws + OFF_WDQ);

  // strip sizing: per row need 16384*4 (gu fp32) + 8192*2 (hq bf16) = 80KB
  size_t avail = ws_size > FIXED_END ? ws_size - FIXED_END : 0;
  int S = 128;
  for (int cand = 8192; cand >= 128; cand >>= 1) {
    if ((size_t)cand * 81920ull <= avail) { S = cand; break; }
  }
  float*  gubuf = (float*)(ws + FIXED_END);
  __bf16* hqbuf = (__bf16*)(ws + FIXED_END + (size_t)S * NGU * 4);

  hipMemsetAsync(ws, 0, 64, stream);

  const int n4 = NW / 4;
  k_wabs<<<2048, 256, 0, stream>>>(wg, dsum + 0, n4);
  k_wabs<<<2048, 256, 0, stream>>>(wu, dsum + 1, n4);
  k_wabs<<<2048, 256, 0, stream>>>(wd, dsum + 2, n4);

  k_quant_w<<<2048, 256, 0, stream>>>(wg, wgq, dsum + 0, n4);
  k_quant_w<<<2048, 256, 0, stream>>>(wu, wuq, dsum + 1, n4);
  k_quant_w<<<2048, 256, 0, stream>>>(wd, wdq, dsum + 2, n4);

  k_quant_x<<<TOK, 256, 0, stream>>>(x, xq, sx);

  for (int base = 0; base < TOK; base += S) {
    // [gate | up] = xq_strip @ [wgq; wuq]^T   (N = 16384, single accumulator)
    k_gemm<<<dim3(NGU / 128, S / 128), 256, 0, stream>>>(
        xq + (size_t)base * DM, wgq, gubuf, sx + base,
        dsum + 0, dsum + 1, DF, NGU, DM);

    k_gufuse<<<S, 256, 0, stream>>>(gubuf, hqbuf, sh + base);

    k_gemm<<<dim3(DM / 128, S / 128), 256, 0, stream>>>(
        hqbuf, wdq, out + (size_t)base * DM, sh + base,
        dsum + 2, dsum + 2, 1 << 30, DM, DF);
  }
}

// Round 4
// 1051.127 us; speedup vs baseline: 2.5378x; 2.5378x over previous
//
#include <hip/hip_runtime.h>
#include <math.h>

#define EPSQ 1e-5f
#define TOK 8192
#define DM 2048
#define DF 8192
#define NW (DM*DF)
#define NGU 16384   // concatenated gate+up output width

typedef float f32x4 __attribute__((ext_vector_type(4)));
typedef int   int32x4 __attribute__((ext_vector_type(4)));
typedef char  i8x4 __attribute__((ext_vector_type(4)));
typedef char  i8x8 __attribute__((ext_vector_type(8)));

// ---- fixed workspace layout (bytes) ----
#define OFF_DSUM 0ull                                // 3 doubles
#define OFF_SX   (4ull<<10)                          // 8192 f32
#define OFF_SH   (40ull<<10)                         // 8192 f32
#define OFF_XQ   (1ull<<20)                          // 16MB i8 [8192][2048]
#define OFF_WGQ  (OFF_XQ  + (16ull<<20))             // 16MB i8 [8192][2048]
#define OFF_WUQ  (OFF_WGQ + (16ull<<20))             // 16MB (contiguous after WGQ)
#define OFF_WDQ  (OFF_WUQ + (16ull<<20))             // 16MB i8 [2048][8192]
#define OFF_HQ   (OFF_WDQ + (16ull<<20))             // 64MB i8 [8192][8192]
#define FIXED_END (OFF_HQ + (64ull<<20))             // 129MB
// strip region (after FIXED_END): gu fp32 [S][16384]

#define GLL(gp, lp) __builtin_amdgcn_global_load_lds( \
    (const __attribute__((address_space(1))) unsigned int*)(gp), \
    (__attribute__((address_space(3))) unsigned int*)(lp), 16, 0, 0)

// ---- |w| sum (for absmean scale), double-precision total ----
__global__ void k_wabs(const float* __restrict__ w, double* __restrict__ dsum, int n4) {
  const f32x4* w4 = (const f32x4*)w;
  float s = 0.f;
  for (int i = blockIdx.x * blockDim.x + threadIdx.x; i < n4; i += gridDim.x * blockDim.x) {
    f32x4 v = w4[i];
    s += fabsf(v.x) + fabsf(v.y) + fabsf(v.z) + fabsf(v.w);
  }
  __shared__ float red[256];
  red[threadIdx.x] = s; __syncthreads();
  for (int o = 128; o > 0; o >>= 1) {
    if (threadIdx.x < o) red[threadIdx.x] += red[threadIdx.x + o];
    __syncthreads();
  }
  if (threadIdx.x == 0) atomicAdd(dsum, (double)red[0]);
}

// ---- ternary-quantize weights -> int8 {-1,0,1} ----
__global__ void k_quant_w(const float* __restrict__ w, char* __restrict__ wq,
                          const double* __restrict__ dsum, int n4) {
  float scale = (float)(*dsum / (double)NW) + EPSQ;
  const f32x4* w4 = (const f32x4*)w;
  for (int i = blockIdx.x * blockDim.x + threadIdx.x; i < n4; i += gridDim.x * blockDim.x) {
    f32x4 v = w4[i];
    i8x4 o;
#pragma unroll
    for (int c = 0; c < 4; c++) {
      float q = rintf(v[c] / scale);
      q = fminf(1.f, fmaxf(-1.f, q));
      o[c] = (char)(int)q;
    }
    *(i8x4*)&wq[(size_t)i * 4] = o;
  }
}

// ---- per-token int8 quantize x -> int8 + scale ----
__global__ void k_quant_x(const float* __restrict__ x, char* __restrict__ xq,
                          float* __restrict__ sx) {
  const int row = blockIdx.x;
  const int tid = threadIdx.x;
  const f32x4* xr = (const f32x4*)(x + (size_t)row * DM);
  f32x4 v0 = xr[tid * 2], v1 = xr[tid * 2 + 1];
  float m = 0.f;
#pragma unroll
  for (int c = 0; c < 4; c++) m = fmaxf(m, fmaxf(fabsf(v0[c]), fabsf(v1[c])));
  __shared__ float red[256];
  red[tid] = m; __syncthreads();
  for (int o = 128; o > 0; o >>= 1) {
    if (tid < o) red[tid] = fmaxf(red[tid], red[tid + o]);
    __syncthreads();
  }
  float sc = fmaxf(red[0], EPSQ) / 127.f;
  if (tid == 0) sx[row] = sc;
  i8x8 o;
#pragma unroll
  for (int c = 0; c < 4; c++) {
    float q0 = fminf(127.f, fmaxf(-128.f, rintf(v0[c] / sc)));
    float q1 = fminf(127.f, fmaxf(-128.f, rintf(v1[c] / sc)));
    o[c] = (char)(int)q0; o[c + 4] = (char)(int)q1;
  }
  *(i8x8*)&xq[(size_t)row * DM + tid * 8] = o;
}

// ---- fused h = sigmoid(gate)*up, row-max, int8 quantize ----
// gu row layout: [0,8192) = gate, [8192,16384) = up (both fp32-scaled)
__global__ void k_gufuse(const float* __restrict__ gu, char* __restrict__ hq,
                         float* __restrict__ sh) {
  const int row = blockIdx.x;
  const int tid = threadIdx.x;
  const f32x4* g4 = (const f32x4*)(gu + (size_t)row * NGU);
  const f32x4* u4 = g4 + (DF / 4);
  float h[32];
  float m = 0.f;
#pragma unroll
  for (int j = 0; j < 8; j++) {
    f32x4 g = g4[tid * 8 + j];
    f32x4 u = u4[tid * 8 + j];
#pragma unroll
    for (int c = 0; c < 4; c++) {
      float v = u[c] / (1.f + expf(-g[c]));   // sigmoid(g)*u
      h[j * 4 + c] = v;
      m = fmaxf(m, fabsf(v));
    }
  }
  __shared__ float red[256];
  red[tid] = m; __syncthreads();
  for (int o = 128; o > 0; o >>= 1) {
    if (tid < o) red[tid] = fmaxf(red[tid], red[tid + o]);
    __syncthreads();
  }
  float sc = fmaxf(red[0], EPSQ) / 127.f;
  if (tid == 0) sh[row] = sc;
#pragma unroll
  for (int jj = 0; jj < 4; jj++) {
    i8x8 o;
#pragma unroll
    for (int c = 0; c < 8; c++) {
      float q = fminf(127.f, fmaxf(-128.f, rintf(h[jj * 8 + c] / sc)));
      o[c] = (char)(int)q;
    }
    *(i8x8*)&hq[(size_t)row * DF + tid * 32 + jj * 8] = o;
  }
}

// ---- int8 MFMA GEMM, both operands K-major.
// C[m,n] = (sum_k A[m,k]*B[n,k]) * rowscale[m] * sw,  sw selected by n0 vs colsplit.
__global__ __launch_bounds__(256)
void k_gemm(const char* __restrict__ A, const char* __restrict__ B,
            float* __restrict__ C, const float* __restrict__ rowscale,
            const double* __restrict__ dsumA, const double* __restrict__ dsumB,
            int colsplit, int N, int K) {
  __shared__ __align__(16) char sA[128 * 64];
  __shared__ __align__(16) char sB[128 * 64];

  const int tid = threadIdx.x;
  const int wv = tid >> 6;
  const int lane = tid & 63;
  const int wm = wv >> 1, wn = wv & 1;
  const int lr = lane & 15;
  const int kb = (lane >> 4) * 16;   // byte offset within 64B K-row

  const int m0 = blockIdx.y * 128;
  const int n0 = blockIdx.x * 128;

  const float sw = (n0 < colsplit)
      ? (float)(*dsumA / (double)NW) + EPSQ
      : (float)(*dsumB / (double)NW) + EPSQ;

  const int srow = tid >> 2;           // 0..63
  const int scol = (tid & 3) * 16;     // 0/16/32/48 bytes
  const int ldsb = wv * 1024;          // wave-uniform LDS staging base (bytes)

  int32x4 acc[4][4];
  const int32x4 z4 = {0, 0, 0, 0};
#pragma unroll
  for (int i = 0; i < 4; i++)
#pragma unroll
    for (int j = 0; j < 4; j++) acc[i][j] = z4;

  const char* gA = A + (size_t)(m0 + srow) * K + scol;
  const char* gB = B + (size_t)(n0 + srow) * K + scol;
  const size_t rstep = (size_t)64 * K;

  for (int k0 = 0; k0 < K; k0 += 64) {
    GLL(gA + k0, sA + ldsb);
    GLL(gA + k0 + rstep, sA + 4096 + ldsb);
    GLL(gB + k0, sB + ldsb);
    GLL(gB + k0 + rstep, sB + 4096 + ldsb);
    __syncthreads();

    int32x4 af[4], bfr[4];
#pragma unroll
    for (int m = 0; m < 4; m++)
      af[m] = *(const int32x4*)&sA[(wm * 64 + m * 16 + lr) * 64 + kb];
#pragma unroll
    for (int n = 0; n < 4; n++)
      bfr[n] = *(const int32x4*)&sB[(wn * 64 + n * 16 + lr) * 64 + kb];
#pragma unroll
    for (int m = 0; m < 4; m++)
#pragma unroll
      for (int n = 0; n < 4; n++)
        acc[m][n] = __builtin_amdgcn_mfma_i32_16x16x64_i8(af[m], bfr[n], acc[m][n], 0, 0, 0);
    __syncthreads();
  }

  // epilogue: C/D layout col = lane&15, row = (lane>>4)*4 + j (shape-determined)
  float rs[4][4];
#pragma unroll
  for (int m = 0; m < 4; m++)
#pragma unroll
    for (int j = 0; j < 4; j++)
      rs[m][j] = rowscale[m0 + wm * 64 + m * 16 + (lane >> 4) * 4 + j] * sw;

#pragma unroll
  for (int m = 0; m < 4; m++)
#pragma unroll
    for (int n = 0; n < 4; n++)
#pragma unroll
      for (int j = 0; j < 4; j++) {
        int row = m0 + wm * 64 + m * 16 + (lane >> 4) * 4 + j;
        int col = n0 + wn * 64 + n * 16 + lr;
        C[(size_t)row * N + col] = (float)acc[m][n][j] * rs[m][j];
      }
}

extern "C" void kernel_launch(void* const* d_in, const int* in_sizes, int n_in,
                              void* d_out, int out_size, void* d_ws, size_t ws_size,
                              hipStream_t stream) {
  const float* x  = (const float*)d_in[0];
  const float* wg = (const float*)d_in[1];
  const float* wu = (const float*)d_in[2];
  const float* wd = (const float*)d_in[3];
  float* out = (float*)d_out;
  char* ws = (char*)d_ws;

  double* dsum = (double*)(ws + OFF_DSUM);
  float* sx = (float*)(ws + OFF_SX);
  float* sh = (float*)(ws + OFF_SH);
  char* xq  = ws + OFF_XQ;
  char* wgq = ws + OFF_WGQ;   // wgq..wuq contiguous = [16384][2048]
  char* wuq = ws + OFF_WUQ;
  char* wdq = ws + OFF_WDQ;
  char* hq  = ws + OFF_HQ;    // full [8192][8192] int8

  // strip sizing: per row need 16384*4 B (gu fp32) = 64KB
  size_t avail = ws_size > FIXED_END ? ws_size - FIXED_END : 0;
  int S = 128;
  for (int cand = 8192; cand >= 128; cand >>= 1) {
    if ((size_t)cand * 65536ull <= avail) { S = cand; break; }
  }
  float* gubuf = (float*)(ws + FIXED_END);

  hipMemsetAsync(ws, 0, 64, stream);

  const int n4 = NW / 4;
  k_wabs<<<2048, 256, 0, stream>>>(wg, dsum + 0, n4);
  k_wabs<<<2048, 256, 0, stream>>>(wu, dsum + 1, n4);
  k_wabs<<<2048, 256, 0, stream>>>(wd, dsum + 2, n4);

  k_quant_w<<<2048, 256, 0, stream>>>(wg, wgq, dsum + 0, n4);
  k_quant_w<<<2048, 256, 0, stream>>>(wu, wuq, dsum + 1, n4);
  k_quant_w<<<2048, 256, 0, stream>>>(wd, wdq, dsum + 2, n4);

  k_quant_x<<<TOK, 256, 0, stream>>>(x, xq, sx);

  for (int base = 0; base < TOK; base += S) {
    // [gate | up] = xq_strip @ [wgq; wuq]^T  (N = 16384, i8 MFMA)
    k_gemm<<<dim3(NGU / 128, S / 128), 256, 0, stream>>>(
        xq + (size_t)base * DM, wgq, gubuf, sx + base,
        dsum + 0, dsum + 1, DF, NGU, DM);

    k_gufuse<<<S, 256, 0, stream>>>(gubuf, hq + (size_t)base * DF, sh + base);
  }

  // single down-projection GEMM over all rows: grid 16 x 64 = 1024 blocks
  k_gemm<<<dim3(DM / 128, TOK / 128), 256, 0, stream>>>(
      hq, wdq, out, sh, dsum + 2, dsum + 2, 1 << 30, DM, DF);
}

// Round 5
// 865.902 us; speedup vs baseline: 3.0806x; 1.2139x over previous
//
#include <hip/hip_runtime.h>
#include <math.h>

#define EPSQ 1e-5f
#define TOK 8192
#define DM 2048
#define DF 8192
#define NW (DM*DF)
#define NGU 16384   // concatenated gate+up output width

typedef float f32x4 __attribute__((ext_vector_type(4)));
typedef int   int32x4 __attribute__((ext_vector_type(4)));
typedef char  i8x4 __attribute__((ext_vector_type(4)));
typedef char  i8x8 __attribute__((ext_vector_type(8)));

// ---- fixed workspace layout (bytes) ----
#define OFF_DSUM 0ull                                // 3 doubles
#define OFF_SX   (4ull<<10)                          // 8192 f32
#define OFF_SH   (40ull<<10)                         // 8192 f32
#define OFF_XQ   (1ull<<20)                          // 16MB i8 [8192][2048]
#define OFF_WGQ  (OFF_XQ  + (16ull<<20))             // 16MB i8 [8192][2048]
#define OFF_WUQ  (OFF_WGQ + (16ull<<20))             // 16MB (contiguous after WGQ)
#define OFF_WDQ  (OFF_WUQ + (16ull<<20))             // 16MB i8 [2048][8192]
#define OFF_HQ   (OFF_WDQ + (16ull<<20))             // 64MB i8 [8192][8192]
#define FIXED_END (OFF_HQ + (64ull<<20))             // 129MB
// strip region (after FIXED_END): gu fp32 [S][16384]

#define GLL(gp, lp) __builtin_amdgcn_global_load_lds( \
    (const __attribute__((address_space(1))) unsigned int*)(gp), \
    (__attribute__((address_space(3))) unsigned int*)(lp), 16, 0, 0)

// ---- |w| sum (for absmean scale), double-precision total ----
__global__ void k_wabs(const float* __restrict__ w, double* __restrict__ dsum, int n4) {
  const f32x4* w4 = (const f32x4*)w;
  float s = 0.f;
  for (int i = blockIdx.x * blockDim.x + threadIdx.x; i < n4; i += gridDim.x * blockDim.x) {
    f32x4 v = w4[i];
    s += fabsf(v.x) + fabsf(v.y) + fabsf(v.z) + fabsf(v.w);
  }
  __shared__ float red[256];
  red[threadIdx.x] = s; __syncthreads();
  for (int o = 128; o > 0; o >>= 1) {
    if (threadIdx.x < o) red[threadIdx.x] += red[threadIdx.x + o];
    __syncthreads();
  }
  if (threadIdx.x == 0) atomicAdd(dsum, (double)red[0]);
}

// ---- ternary-quantize weights -> int8 {-1,0,1} ----
__global__ void k_quant_w(const float* __restrict__ w, char* __restrict__ wq,
                          const double* __restrict__ dsum, int n4) {
  float scale = (float)(*dsum / (double)NW) + EPSQ;
  const f32x4* w4 = (const f32x4*)w;
  for (int i = blockIdx.x * blockDim.x + threadIdx.x; i < n4; i += gridDim.x * blockDim.x) {
    f32x4 v = w4[i];
    i8x4 o;
#pragma unroll
    for (int c = 0; c < 4; c++) {
      float q = rintf(v[c] / scale);
      q = fminf(1.f, fmaxf(-1.f, q));
      o[c] = (char)(int)q;
    }
    *(i8x4*)&wq[(size_t)i * 4] = o;
  }
}

// ---- per-token int8 quantize x -> int8 + scale ----
__global__ void k_quant_x(const float* __restrict__ x, char* __restrict__ xq,
                          float* __restrict__ sx) {
  const int row = blockIdx.x;
  const int tid = threadIdx.x;
  const f32x4* xr = (const f32x4*)(x + (size_t)row * DM);
  f32x4 v0 = xr[tid * 2], v1 = xr[tid * 2 + 1];
  float m = 0.f;
#pragma unroll
  for (int c = 0; c < 4; c++) m = fmaxf(m, fmaxf(fabsf(v0[c]), fabsf(v1[c])));
  __shared__ float red[256];
  red[tid] = m; __syncthreads();
  for (int o = 128; o > 0; o >>= 1) {
    if (tid < o) red[tid] = fmaxf(red[tid], red[tid + o]);
    __syncthreads();
  }
  float sc = fmaxf(red[0], EPSQ) / 127.f;
  if (tid == 0) sx[row] = sc;
  i8x8 o;
#pragma unroll
  for (int c = 0; c < 4; c++) {
    float q0 = fminf(127.f, fmaxf(-128.f, rintf(v0[c] / sc)));
    float q1 = fminf(127.f, fmaxf(-128.f, rintf(v1[c] / sc)));
    o[c] = (char)(int)q0; o[c + 4] = (char)(int)q1;
  }
  *(i8x8*)&xq[(size_t)row * DM + tid * 8] = o;
}

// ---- fused h = sigmoid(gate)*up, row-max, int8 quantize ----
__global__ void k_gufuse(const float* __restrict__ gu, char* __restrict__ hq,
                         float* __restrict__ sh) {
  const int row = blockIdx.x;
  const int tid = threadIdx.x;
  const f32x4* g4 = (const f32x4*)(gu + (size_t)row * NGU);
  const f32x4* u4 = g4 + (DF / 4);
  float h[32];
  float m = 0.f;
#pragma unroll
  for (int j = 0; j < 8; j++) {
    f32x4 g = g4[tid * 8 + j];
    f32x4 u = u4[tid * 8 + j];
#pragma unroll
    for (int c = 0; c < 4; c++) {
      float v = u[c] / (1.f + expf(-g[c]));   // sigmoid(g)*u
      h[j * 4 + c] = v;
      m = fmaxf(m, fabsf(v));
    }
  }
  __shared__ float red[256];
  red[tid] = m; __syncthreads();
  for (int o = 128; o > 0; o >>= 1) {
    if (tid < o) red[tid] = fmaxf(red[tid], red[tid + o]);
    __syncthreads();
  }
  float sc = fmaxf(red[0], EPSQ) / 127.f;
  if (tid == 0) sh[row] = sc;
#pragma unroll
  for (int jj = 0; jj < 4; jj++) {
    i8x8 o;
#pragma unroll
    for (int c = 0; c < 8; c++) {
      float q = fminf(127.f, fmaxf(-128.f, rintf(h[jj * 8 + c] / sc)));
      o[c] = (char)(int)q;
    }
    *(i8x8*)&hq[(size_t)row * DF + tid * 32 + jj * 8] = o;
  }
}

// ---- 256x256-tile i8 MFMA GEMM, BK=128, 8 waves (2Mx4N), double-buffered LDS,
//      counted-vmcnt pipeline (T3/T4), LDS XOR-swizzle via pre-swizzled GLL
//      source (rule #21), setprio around MFMA clusters (T5), XCD swizzle (T1).
// C[m,n] = (sum_k A[m,k]*B[n,k]) * rowscale[m] * sw,  sw selected by n0 vs colsplit.
__global__ __launch_bounds__(512)
void k_gemm8(const char* __restrict__ A, const char* __restrict__ B,
             float* __restrict__ C, const float* __restrict__ rowscale,
             const double* __restrict__ dsumA, const double* __restrict__ dsumB,
             int colsplit, int N, int K) {
  __shared__ __align__(16) char sA[2][256 * 128];
  __shared__ __align__(16) char sB[2][256 * 128];

  const int tid = threadIdx.x;
  const int wv = tid >> 6;          // 0..7
  const int lane = tid & 63;
  const int wm = wv >> 2;           // 0..1  (M half: 128 rows)
  const int wn = wv & 3;            // 0..3  (N quarter: 64 cols)
  const int lr = lane & 15;
  const int g = lane >> 4;          // 0..3  (16B k-slot group)

  // bijective XCD swizzle (nwg % 8 == 0 for all our grids)
  const int nwg = gridDim.x * gridDim.y;
  const int bid = blockIdx.y * gridDim.x + blockIdx.x;
  const int lid = (bid & 7) * (nwg >> 3) + (bid >> 3);
  const int gx = N >> 8;
  const int n0 = (lid % gx) << 8;
  const int m0 = (lid / gx) << 8;

  const float sw = (n0 < colsplit)
      ? (float)(*dsumA / (double)NW) + EPSQ
      : (float)(*dsumB / (double)NW) + EPSQ;

  // staging: wave wv stages rows [wv*32, wv*32+32), 4 chunks of 8 rows (A and B).
  // LDS is linear [row][128B]; swizzle done by fetching global slot (l&7)^(l>>3).
  const int prow = lane >> 3;                    // 0..7 row within chunk
  const int pcol = ((lane & 7) ^ prow) << 4;     // pre-swizzled 16B slot
  const char* gAl = A + (size_t)(m0 + wv * 32 + prow) * K + pcol;
  const char* gBl = B + (size_t)(n0 + wv * 32 + prow) * K + pcol;
  const size_t phstep = (size_t)8 * K;           // +8 rows per chunk

  int32x4 acc[8][4];
  const int32x4 z4 = {0, 0, 0, 0};
#pragma unroll
  for (int m = 0; m < 8; m++)
#pragma unroll
    for (int n = 0; n < 4; n++) acc[m][n] = z4;

  const int NT = K >> 7;   // K-tiles of 128

  // prologue: stage tile 0 into buf 0
#pragma unroll
  for (int p = 0; p < 4; p++) {
    GLL(gAl + (size_t)p * phstep, &sA[0][(wv * 4 + p) << 10]);
    GLL(gBl + (size_t)p * phstep, &sB[0][(wv * 4 + p) << 10]);
  }

  for (int t = 0; t < NT; ++t) {
    const int b = t & 1;
    if (t + 1 < NT) {
      // prefetch tile t+1 into other buffer (readers of it finished before
      // the previous end-of-tile barrier)
      const size_t koff = (size_t)(t + 1) << 7;
#pragma unroll
      for (int p = 0; p < 4; p++) {
        GLL(gAl + (size_t)p * phstep + koff, &sA[b ^ 1][(wv * 4 + p) << 10]);
        GLL(gBl + (size_t)p * phstep + koff, &sB[b ^ 1][(wv * 4 + p) << 10]);
      }
      asm volatile("s_waitcnt vmcnt(8)" ::: "memory");  // tile t's 8 done, t+1 in flight
    } else {
      asm volatile("s_waitcnt vmcnt(0)" ::: "memory");
    }
    __builtin_amdgcn_s_barrier();      // all waves: tile t staged
    asm volatile("" ::: "memory");

    // B fragments for whole tile (8 x ds_read_b128, swizzled)
    int32x4 bF[4][2];
#pragma unroll
    for (int n = 0; n < 4; n++)
#pragma unroll
      for (int kk = 0; kk < 2; kk++)
        bF[n][kk] = *(const int32x4*)&sB[b][(wn * 64 + n * 16 + lr) * 128 +
                                           (((g + kk * 4) ^ (lr & 7)) << 4)];

    // 4 phases: 2 m-reps each, 16 MFMA per phase
#pragma unroll
    for (int p = 0; p < 4; p++) {
      int32x4 aF[2][2];
#pragma unroll
      for (int i = 0; i < 2; i++)
#pragma unroll
        for (int kk = 0; kk < 2; kk++)
          aF[i][kk] = *(const int32x4*)&sA[b][(wm * 128 + (2 * p + i) * 16 + lr) * 128 +
                                             (((g + kk * 4) ^ (lr & 7)) << 4)];
      __builtin_amdgcn_s_setprio(1);
#pragma unroll
      for (int i = 0; i < 2; i++)
#pragma unroll
        for (int n = 0; n < 4; n++)
#pragma unroll
          for (int kk = 0; kk < 2; kk++)
            acc[2 * p + i][n] = __builtin_amdgcn_mfma_i32_16x16x64_i8(
                aF[i][kk], bF[n][kk], acc[2 * p + i][n], 0, 0, 0);
      __builtin_amdgcn_s_setprio(0);
    }
    asm volatile("" ::: "memory");
    __builtin_amdgcn_s_barrier();      // all waves done reading buf b
  }

  // epilogue: C/D layout col = lane&15, row = (lane>>4)*4 + j
#pragma unroll
  for (int m = 0; m < 8; m++) {
#pragma unroll
    for (int j = 0; j < 4; j++) {
      const int row = m0 + wm * 128 + m * 16 + g * 4 + j;
      const float rs = rowscale[row] * sw;
#pragma unroll
      for (int n = 0; n < 4; n++) {
        const int col = n0 + wn * 64 + n * 16 + lr;
        C[(size_t)row * N + col] = (float)acc[m][n][j] * rs;
      }
    }
  }
}

extern "C" void kernel_launch(void* const* d_in, const int* in_sizes, int n_in,
                              void* d_out, int out_size, void* d_ws, size_t ws_size,
                              hipStream_t stream) {
  const float* x  = (const float*)d_in[0];
  const float* wg = (const float*)d_in[1];
  const float* wu = (const float*)d_in[2];
  const float* wd = (const float*)d_in[3];
  float* out = (float*)d_out;
  char* ws = (char*)d_ws;

  double* dsum = (double*)(ws + OFF_DSUM);
  float* sx = (float*)(ws + OFF_SX);
  float* sh = (float*)(ws + OFF_SH);
  char* xq  = ws + OFF_XQ;
  char* wgq = ws + OFF_WGQ;   // wgq..wuq contiguous = [16384][2048]
  char* wuq = ws + OFF_WUQ;
  char* wdq = ws + OFF_WDQ;
  char* hq  = ws + OFF_HQ;    // full [8192][8192] int8

  // strip sizing: per row need 16384*4 B (gu fp32); S multiple of 256
  size_t avail = ws_size > FIXED_END ? ws_size - FIXED_END : 0;
  int S = 256;
  for (int cand = 8192; cand >= 256; cand >>= 1) {
    if ((size_t)cand * 65536ull <= avail) { S = cand; break; }
  }
  float* gubuf = (float*)(ws + FIXED_END);

  hipMemsetAsync(ws, 0, 64, stream);

  const int n4 = NW / 4;
  k_wabs<<<2048, 256, 0, stream>>>(wg, dsum + 0, n4);
  k_wabs<<<2048, 256, 0, stream>>>(wu, dsum + 1, n4);
  k_wabs<<<2048, 256, 0, stream>>>(wd, dsum + 2, n4);

  k_quant_w<<<2048, 256, 0, stream>>>(wg, wgq, dsum + 0, n4);
  k_quant_w<<<2048, 256, 0, stream>>>(wu, wuq, dsum + 1, n4);
  k_quant_w<<<2048, 256, 0, stream>>>(wd, wdq, dsum + 2, n4);

  k_quant_x<<<TOK, 256, 0, stream>>>(x, xq, sx);

  for (int base = 0; base < TOK; base += S) {
    // [gate | up] = xq_strip @ [wgq; wuq]^T  (N = 16384)
    k_gemm8<<<dim3(NGU / 256, S / 256), 512, 0, stream>>>(
        xq + (size_t)base * DM, wgq, gubuf, sx + base,
        dsum + 0, dsum + 1, DF, NGU, DM);

    k_gufuse<<<S, 256, 0, stream>>>(gubuf, hq + (size_t)base * DF, sh + base);
  }

  // single down-projection GEMM over all rows
  k_gemm8<<<dim3(DM / 256, TOK / 256), 512, 0, stream>>>(
      hq, wdq, out, sh, dsum + 2, dsum + 2, 1 << 30, DM, DF);
}